// Round 15
// baseline (1627.841 us; speedup 1.0000x reference)
//
#include <hip/hip_runtime.h>
#include <stdint.h>

#define N_ROWS 262144
#define D_DIM  1024
#define H_DIM  512
#define N_SEG  512

typedef __attribute__((ext_vector_type(4)))  float  f32x4;
typedef __attribute__((ext_vector_type(16))) float  f32x16;
typedef __attribute__((ext_vector_type(8)))  __bf16 bf16x8;
typedef __attribute__((ext_vector_type(8)))  unsigned short u16x8;

static __device__ __forceinline__ unsigned short c2bf(float f) {
  union { __bf16 b; unsigned short u; } c; c.b = (__bf16)f; return c.u;
}
static __device__ __forceinline__ float fast_tanh(float u) {
  return 1.0f - 2.0f / (__expf(2.0f * u) + 1.0f);
}

// ---------------- kernel 0: W1,W2 f32 -> bf16 frag image (32-vcol frags) ----
// Frag for (hs, kt, cg): 1 KB = 64 lanes x 16B. Lane l: vcol c = cg*32+(l&31)
// in slice [0,128); mat = c&1 (0=W1,1=W2); h = hs*64 + (c>>1);
// k = kt*16 + (l>>5)*8 + e.  elem idx = (hs<<14 | kt<<8 | cg<<6 | l)*8 + e.
__global__ void cvt_w(const float* __restrict__ W1, const float* __restrict__ W2,
                      unsigned short* __restrict__ wbf) {
  int gid = blockIdx.x * 256 + threadIdx.x;      // 131072 frags-of-8
  int l   = gid & 63;
  int cg  = (gid >> 6) & 3;
  int kt  = (gid >> 8) & 63;
  int hs  = gid >> 14;                           // 0..7
  int c   = (cg << 5) + (l & 31);
  int h   = (hs << 6) + (c >> 1);
  int k0  = (kt << 4) + ((l >> 5) << 3);
  const float* src = ((c & 1) ? W2 : W1) + h * 1024 + k0;
  f32x4 f0 = *(const f32x4*)src;
  f32x4 f1 = *(const f32x4*)(src + 4);
  u16x8 v;
  v[0]=c2bf(f0[0]); v[1]=c2bf(f0[1]); v[2]=c2bf(f0[2]); v[3]=c2bf(f0[3]);
  v[4]=c2bf(f1[0]); v[5]=c2bf(f1[1]); v[6]=c2bf(f1[2]); v[7]=c2bf(f1[3]);
  *(u16x8*)(wbf + (size_t)gid * 8) = v;
}

// ---------------- kernel 1: partial (m,s,n) per (row, 64-h slice) ----------
// Block = 128 rows x 128 vcols (64 h x {u,v}); 512 thr, 8 waves = 2rg x 4cg;
// wave = 64r x 32vc via mfma 32x32x16: acc = 2 x f32x16 (32 AGPR only).
// W reused across 2 row-frags (0.5 KB/MFMA -> 64 B/cyc/CU L2, half of R7).
// launch_bounds(512,6) -> 3 blocks/CU, 6 waves/SIMD.
// A staged to LDS in FRAG-LINEAR layout (lane-contiguous 1KB frags):
// conflict-free ds_read AND ds_write. W ping-pong 1 kstep ahead from image.
// Barriers: lgkmcnt(0)+s_barrier only (vmcnt never drained in loop).
#define MF32(A, B, C) __builtin_amdgcn_mfma_f32_32x32x16_bf16((A), (B), (C), 0, 0, 0)

// A-LDS layout per 16KB buffer (64k subtile): [kq 4][rowgrp 4][lane 64][16B];
// frag (kq, grp) holds rows grp*32+(l&31), k = kq*16 + (l>>5)*8 + e.
#define ALOAD(T) do { \
  const float* _p = xsrc + ((T) << 6); \
  r0 = *(const f32x4*)_p; r1 = *(const f32x4*)(_p + 4); \
  r2 = *(const f32x4*)(_p + 8); r3 = *(const f32x4*)(_p + 12); \
} while (0)

#define PACKA(BUF) do { \
  u16x8 va, vb; \
  va[0]=c2bf(r0[0]); va[1]=c2bf(r0[1]); va[2]=c2bf(r0[2]); va[3]=c2bf(r0[3]); \
  va[4]=c2bf(r1[0]); va[5]=c2bf(r1[1]); va[6]=c2bf(r1[2]); va[7]=c2bf(r1[3]); \
  vb[0]=c2bf(r2[0]); vb[1]=c2bf(r2[1]); vb[2]=c2bf(r2[2]); vb[3]=c2bf(r2[3]); \
  vb[4]=c2bf(r3[0]); vb[5]=c2bf(r3[1]); vb[6]=c2bf(r3[2]); vb[7]=c2bf(r3[3]); \
  *(u16x8*)(lds + (BUF) + wb0) = va; \
  *(u16x8*)(lds + (BUF) + wb0 + 512) = vb; \
} while (0)

#define KST(KQ, BUF, WU, WL, KT) do { \
  WL = *(const bf16x8*)(wsrc + ((uint32_t)((KT) + 1) << 11)); \
  bf16x8 A0 = *(const bf16x8*)(lds + (BUF) + ((KQ) << 12) + ra); \
  bf16x8 A1 = *(const bf16x8*)(lds + (BUF) + ((KQ) << 12) + ra + 1024); \
  __builtin_amdgcn_s_setprio(1); \
  acc0 = MF32(A0, WU, acc0); \
  acc1 = MF32(A1, WU, acc1); \
  __builtin_amdgcn_s_setprio(0); \
} while (0)

#define ENDBAR() do { \
  asm volatile("s_waitcnt lgkmcnt(0)" ::: "memory"); \
  __builtin_amdgcn_s_barrier(); \
} while (0)

__launch_bounds__(512, 6)
__global__ void alpha_kernel(const float* __restrict__ x,
                             const unsigned short* __restrict__ wbf,
                             const float* __restrict__ W3,
                             float* __restrict__ pm, float* __restrict__ ps,
                             float* __restrict__ pn)
{
  __shared__ unsigned char lds[32768 + 6144];    // 2 x 16KB A-bufs + 6KB partials
  const int tid  = threadIdx.x;
  const int lane = tid & 63;
  const int wid  = tid >> 6;                     // 0..7
  const int rg   = wid >> 2;                     // 0..1  (64-row half)
  const int cg   = wid & 3;                      // 0..3  (32-vcol quarter)
  const int l31  = lane & 31;
  const int hi   = lane >> 5;
  const int bid  = blockIdx.x;
  const int rt   = ((bid >> 6) << 3) + (bid & 7);   // 0..2047 rowtile (hs same XCD)
  const int hs   = (bid >> 3) & 7;                  // 0..7  64-h slice
  const int row0 = rt << 7;                         // 128 rows/block

  // A staging: thread -> (kq = tid>>7, row r = tid&127); loads 64B of its row.
  // Writes are lane-contiguous within each wave -> conflict-free.
  const int ar = tid & 127;
  const int akq = tid >> 7;
  const float* xsrc = x + (size_t)(row0 + ar) * 1024 + (akq << 4);
  const uint32_t wb0 = ((uint32_t)akq << 12) + ((uint32_t)(ar >> 5) << 10)
                     + ((uint32_t)(ar & 31) << 4);

  // W source (per-lane, frag image)
  const unsigned short* wsrc =
      wbf + ((((uint32_t)hs << 14) + ((uint32_t)cg << 6) + (uint32_t)lane) << 3);

  // A-frag read base: wave rg reads rowgrps {2rg, 2rg+1}
  const uint32_t ra = ((uint32_t)rg << 11) + ((uint32_t)lane << 4);

  f32x16 acc0, acc1;
  #pragma unroll
  for (int i = 0; i < 16; ++i) { acc0[i] = 0.f; acc1[i] = 0.f; }

  f32x4 r0, r1, r2, r3;
  bf16x8 WA, WB;

  // ---- prologue: sub0 -> buf0; W kt0 -> WA ----
  ALOAD(0);
  PACKA(0);
  WA = *(const bf16x8*)(wsrc);
  ENDBAR();

  // ---- 16 phases of 4 ksteps (k=16 each) ----
  #pragma unroll 1
  for (int t = 0; t < 16; ++t) {
    const uint32_t bufc = (uint32_t)(t & 1) << 14;
    const uint32_t bufn = bufc ^ 16384u;
    if (t < 15) ALOAD(t + 1);                    // issue early; pack late
    KST(0, bufc, WA, WB, t * 4 + 0);
    KST(1, bufc, WB, WA, t * 4 + 1);
    KST(2, bufc, WA, WB, t * 4 + 2);
    KST(3, bufc, WB, WA, t * 4 + 3);
    if (t < 15) PACKA(bufn);                     // auto-waits only the A loads
    ENDBAR();
  }

  // ---- epilogue: per-reg streaming, static, in-register via shfl ----
  // C/D map 32x32 (m74/m101): col = lane&31, row = (reg&3)+8*(reg>>2)+4*hi.
  // vcol c = cg*32 + col; parity(c) = parity(lane): even = u[h], odd = v[h],
  // h = hs*64 + (c>>1). shfl_xor(1) moves gate; xor{2,4,8,16} preserve parity.
  float w3v = W3[(hs << 6) + (((cg << 5) + l31) >> 1)];
  float* pmb = (float*)(lds + 32768);            // [4 cg][128 rows]
  float* psb = pmb + 512;
  float* pnb = psb + 512;

  #pragma unroll
  for (int r = 0; r < 16; ++r) {
    float g = fast_tanh(acc0[r]) * w3v;
    float gs = __shfl_xor(g, 1);
    float m = acc0[r];
    m = fmaxf(m, __shfl_xor(m, 2)); m = fmaxf(m, __shfl_xor(m, 4));
    m = fmaxf(m, __shfl_xor(m, 8)); m = fmaxf(m, __shfl_xor(m, 16));
    float p = __expf(acc0[r] - m);
    float s = p, n = gs * p;
    s += __shfl_xor(s, 2); n += __shfl_xor(n, 2);
    s += __shfl_xor(s, 4); n += __shfl_xor(n, 4);
    s += __shfl_xor(s, 8); n += __shfl_xor(n, 8);
    s += __shfl_xor(s, 16); n += __shfl_xor(n, 16);
    if (l31 == 1) {
      int row = (rg << 6) + (r & 3) + ((r >> 2) << 3) + (hi << 2);
      pmb[(cg << 7) + row] = m; psb[(cg << 7) + row] = s; pnb[(cg << 7) + row] = n;
    }
  }
  #pragma unroll
  for (int r = 0; r < 16; ++r) {
    float g = fast_tanh(acc1[r]) * w3v;
    float gs = __shfl_xor(g, 1);
    float m = acc1[r];
    m = fmaxf(m, __shfl_xor(m, 2)); m = fmaxf(m, __shfl_xor(m, 4));
    m = fmaxf(m, __shfl_xor(m, 8)); m = fmaxf(m, __shfl_xor(m, 16));
    float p = __expf(acc1[r] - m);
    float s = p, n = gs * p;
    s += __shfl_xor(s, 2); n += __shfl_xor(n, 2);
    s += __shfl_xor(s, 4); n += __shfl_xor(n, 4);
    s += __shfl_xor(s, 8); n += __shfl_xor(n, 8);
    s += __shfl_xor(s, 16); n += __shfl_xor(n, 16);
    if (l31 == 1) {
      int row = (rg << 6) + 32 + (r & 3) + ((r >> 2) << 3) + (hi << 2);
      pmb[(cg << 7) + row] = m; psb[(cg << 7) + row] = s; pnb[(cg << 7) + row] = n;
    }
  }
  __syncthreads();
  if (tid < 128) {
    float m0 = pmb[tid], m1 = pmb[128 + tid], m2 = pmb[256 + tid], m3 = pmb[384 + tid];
    float M = fmaxf(fmaxf(m0, m1), fmaxf(m2, m3));
    float e0 = __expf(m0 - M), e1 = __expf(m1 - M), e2 = __expf(m2 - M), e3 = __expf(m3 - M);
    float S  = psb[tid]*e0 + psb[128+tid]*e1 + psb[256+tid]*e2 + psb[384+tid]*e3;
    float Nn = pnb[tid]*e0 + pnb[128+tid]*e1 + pnb[256+tid]*e2 + pnb[384+tid]*e3;
    size_t r = (size_t)(row0 + tid);
    pm[r * 8 + hs] = M;
    ps[r * 8 + hs] = S;
    pn[r * 8 + hs] = Nn;
  }
}

// ---------------- kernel 1b: combine 8 h-slice partials -> a[i] ------------
__global__ void combine_a(const float* __restrict__ pm, const float* __restrict__ ps,
                          const float* __restrict__ pn, float* __restrict__ a) {
  size_t r = (size_t)blockIdx.x * 256 + threadIdx.x;
  float M = -3.4e38f;
  #pragma unroll
  for (int s = 0; s < 8; ++s) M = fmaxf(M, pm[r * 8 + s]);
  float S = 0.f, Nn = 0.f;
  #pragma unroll
  for (int s = 0; s < 8; ++s) {
    float e = __expf(pm[r * 8 + s] - M);
    S  += ps[r * 8 + s] * e;
    Nn += pn[r * 8 + s] * e;
  }
  a[r] = Nn / S;
}

// ---------------- kernel 2: segment softmax weights ----------------
static __device__ __forceinline__ int lower_bound(const int* __restrict__ batch, int key) {
  int lo = 0, hi = N_ROWS;
  while (lo < hi) { int mid = (lo + hi) >> 1; if (batch[mid] < key) lo = mid + 1; else hi = mid; }
  return lo;
}

__global__ void seg_kernel(const float* __restrict__ a, const int* __restrict__ batch,
                           float* __restrict__ w) {
  __shared__ float sm[8];
  int b = blockIdx.x;
  int start = lower_bound(batch, b);
  int end   = lower_bound(batch, b + 1);
  int tid = threadIdx.x;

  float m = -3.4e38f;
  for (int i = start + tid; i < end; i += 256) m = fmaxf(m, a[i]);
  for (int d = 1; d < 64; d <<= 1) m = fmaxf(m, __shfl_xor(m, d));
  if ((tid & 63) == 0) sm[tid >> 6] = m;
  __syncthreads();
  m = fmaxf(fmaxf(sm[0], sm[1]), fmaxf(sm[2], sm[3]));

  float s = 0.f;
  for (int i = start + tid; i < end; i += 256) s += __expf(a[i] - m);
  for (int d = 1; d < 64; d <<= 1) s += __shfl_xor(s, d);
  if ((tid & 63) == 0) sm[4 + (tid >> 6)] = s;
  __syncthreads();
  s = sm[4] + sm[5] + sm[6] + sm[7];

  float rinv = 1.0f / s;
  for (int i = start + tid; i < end; i += 256) w[i] = __expf(a[i] - m) * rinv;
}

// ---------------- kernel 3: z[b] = sum_i w_i * x_i ----------------
__global__ void z_kernel(const float* __restrict__ x, const float* __restrict__ w,
                         const int* __restrict__ batch, float* __restrict__ z) {
  int b = blockIdx.x >> 2, part = blockIdx.x & 3;
  int start = lower_bound(batch, b);
  int end   = lower_bound(batch, b + 1);
  int len = end - start;
  int ps = start + ((len * part) >> 2);
  int pe = start + ((len * (part + 1)) >> 2);
  int col = threadIdx.x << 2;

  f32x4 acc = (f32x4){0.f, 0.f, 0.f, 0.f};
  for (int i = ps; i < pe; ++i) {
    f32x4 xv = *(const f32x4*)(x + ((size_t)i << 10) + col);
    float wi = w[i];
    acc += xv * wi;
  }
  float* zp = z + ((size_t)b << 10) + col;
  atomicAdd(zp + 0, acc[0]);
  atomicAdd(zp + 1, acc[1]);
  atomicAdd(zp + 2, acc[2]);
  atomicAdd(zp + 3, acc[3]);
}

// ---------------- launch ----------------
extern "C" void kernel_launch(void* const* d_in, const int* in_sizes, int n_in,
                              void* d_out, int out_size, void* d_ws, size_t ws_size,
                              hipStream_t stream) {
  const float* x     = (const float*)d_in[0];
  const int*   batch = (const int*)d_in[1];
  const float* W1    = (const float*)d_in[2];
  const float* W2    = (const float*)d_in[3];
  const float* W3    = (const float*)d_in[4];
  float* z = (float*)d_out;

  // ws: [0,2M) wbf ; [2M,3M) a ; [3M,4M) w ; [4M,12M) pm ; [12M,20M) ps ;
  //     [20M,28M) pn
  unsigned short* wbf = (unsigned short*)d_ws;
  float* a  = (float*)((char*)d_ws + (2u << 20));
  float* w  = (float*)((char*)d_ws + (3u << 20));
  float* pm = (float*)((char*)d_ws + (4u << 20));
  float* ps = (float*)((char*)d_ws + (12u << 20));
  float* pn = (float*)((char*)d_ws + (20u << 20));

  (void)hipMemsetAsync(d_out, 0, (size_t)N_SEG * D_DIM * sizeof(float), stream);

  cvt_w<<<512, 256, 0, stream>>>(W1, W2, wbf);

  alpha_kernel<<<16384, 512, 0, stream>>>(x, wbf, W3, pm, ps, pn);

  combine_a<<<N_ROWS / 256, 256, 0, stream>>>(pm, ps, pn, a);

  seg_kernel<<<N_SEG, 256, 0, stream>>>(a, batch, w);

  z_kernel<<<N_SEG * 4, 256, 0, stream>>>(x, w, batch, z);
}